// Round 3
// baseline (557.690 us; speedup 1.0000x reference)
//
#include <hip/hip_runtime.h>
#include <cstdint>
#include <cstddef>

// Problem constants
#define TT   2048
#define BB   64
#define KK   512
#define OO   512
#define NCH  64      // time chunks
#define TC   32      // t-steps per chunk

typedef __attribute__((ext_vector_type(8))) short short8;
typedef __attribute__((ext_vector_type(4))) float f32x4;

__device__ __forceinline__ unsigned short f2bf(float f) {
  unsigned int u = __float_as_uint(f);
  unsigned int rounding = 0x7FFFu + ((u >> 16) & 1u);
  return (unsigned short)((u + rounding) >> 16);
}

// fast gates: v_rcp_f32-based, no division sequence.
// sigmoid: rcp(1+exp(-z)); limits exact (exp->inf => rcp(inf)=0; exp->0 => 1).
__device__ __forceinline__ float fast_sigmoid(float z) {
  return __builtin_amdgcn_rcpf(1.0f + __expf(-z));
}
// tanh(z) = 2*sigmoid(2z) - 1; limits exact at +-inf, no clamp needed.
__device__ __forceinline__ float fast_tanh(float z) {
  return fmaf(2.0f, __builtin_amdgcn_rcpf(1.0f + __expf(-2.0f * z)), -1.0f);
}

__device__ __forceinline__ void async_ld16(const void* g, void* l) {
  __builtin_amdgcn_global_load_lds(
      (const __attribute__((address_space(1))) void*)g,
      (__attribute__((address_space(3))) void*)l, 16, 0, 0);
}

// ---------------- kernel 1: x fp32 -> bf16 ----------------
__global__ void convert_x_k(const float4* __restrict__ x4,
                            ushort4* __restrict__ xb4, int n4) {
  int i = blockIdx.x * blockDim.x + threadIdx.x;
  int stride = gridDim.x * blockDim.x;
  for (; i < n4; i += stride) {
    float4 v = x4[i];
    ushort4 o;
    o.x = f2bf(v.x); o.y = f2bf(v.y); o.z = f2bf(v.z); o.w = f2bf(v.w);
    xb4[i] = o;
  }
}

// ---------------- kernel 2: transpose+convert weights ----------------
// Gt[o][k] = bf16(g[k][o]); Ht likewise. grid (16,16,2), block (32,8)
__global__ void prep_weights_k(const float* __restrict__ g,
                               const float* __restrict__ h,
                               unsigned short* __restrict__ Gt,
                               unsigned short* __restrict__ Ht) {
  __shared__ float tile[32][33];
  const float* src = (blockIdx.z == 0) ? g : h;
  unsigned short* dst = (blockIdx.z == 0) ? Gt : Ht;
  int ox = blockIdx.x * 32;   // o base
  int ky = blockIdx.y * 32;   // k base
  int tx = threadIdx.x, ty = threadIdx.y;
  #pragma unroll
  for (int r = ty; r < 32; r += 8)
    tile[r][tx] = src[(ky + r) * OO + ox + tx];
  __syncthreads();
  #pragma unroll
  for (int r = ty; r < 32; r += 8)
    dst[(size_t)(ox + r) * KK + ky + tx] = f2bf(tile[tx][r]);
}

// ---------------- kernel 3: register-B fused GEMM + gates + scan ----------
// ROUND-3 RESTRUCTURE: 256 blocks (1/CU), 256 threads = 4 waves (1/SIMD).
// Each wave owns 32 o-cols (2 col-blocks of 16) of BOTH G and H: 256 weight
// VGPRs/lane; total ~420 VGPRs, legal at 1 wave/SIMD (launch_bounds(256,1)).
// Why: with 16 cols/wave the 8 waves re-read the whole A-tile 8x from LDS
// (8.2K cyc/iter, the round-0/2 bottleneck). 32 cols/wave halves the read
// amplification: each ds_read_b128 feeds 4 MFMAs -> 256 reads/CU/iter
// (~3.1K cyc), below the 5.0K MFMA floor.
//
// LDS swizzle: slot = chunk ^ ((row&7)<<2). Per read instr the 64 lanes hit
// 32 DISTINCT 16B slots (bits[1:0]=quad, bits[4:2]=k2^(lcol&7)), 2 lanes per
// slot at rows r, r+8 -> 2-way on banks = free (m136). The old ^(row&7)
// swizzle collapsed to 8 slots (8 lanes/slot column) -> the 1.7e7 conflicts.
//
// Ring pipeline kept from round 2: 4 x 32KB half-tiles (64 rows x 256 k),
// 3 stages prefetched, counted s_waitcnt vmcnt(16) (8 DMA instr/wave/stage),
// stage(s+3) issued after the barrier (all waves done reading that buffer).
__global__ __launch_bounds__(256, 1) void rnn_fused5_k(
    const unsigned short* __restrict__ xb,   // [T*B][K] bf16
    const unsigned short* __restrict__ Gt,   // [OO][KK] bf16
    const unsigned short* __restrict__ Ht,   // [OO][KK] bf16
    const float* __restrict__ gb, const float* __restrict__ hb,
    const float* __restrict__ r,  const float* __restrict__ rb,
    float* __restrict__ chunkA, float* __restrict__ chunkB) {
  extern __shared__ __align__(16) unsigned short smem[];  // 4 x [64][256]

  const int tid  = threadIdx.x;
  const int wave = tid >> 6;   // 0..3
  const int lane = tid & 63;
  const int quad = lane >> 4;
  const int lcol = lane & 15;

  // bi = ot*64 + c: the 4 o-tiles of chunk c share bi%8 -> same XCD (L2 reuse)
  const int bi = blockIdx.x;
  const int ot = bi >> 6;      // 0..3
  const int c  = bi & 63;      // 0..63
  const int o0 = ot * 128 + wave * 32 + lcol;  // col-block cb adds 16

  float gbv[2], hbv[2], rv[2], rbv[2];
  #pragma unroll
  for (int cb = 0; cb < 2; ++cb) {
    int o = o0 + cb * 16;
    gbv[cb] = gb[o]; hbv[cb] = hb[o];
    rv[cb]  = r[o];  rbv[cb] = rb[o];
  }

  // ---- weights into registers: 2 col-blocks x K512 x {G,H} = 256 VGPRs ----
  // Bg[cb][K16] covers k in [K16*32 + quad*8, +8) for o-col o0+cb*16.
  short8 Bg[2][16], Bh[2][16];
  #pragma unroll
  for (int cb = 0; cb < 2; ++cb) {
    const unsigned short* gp = Gt + (size_t)(o0 + cb * 16) * KK + quad * 8;
    const unsigned short* hp = Ht + (size_t)(o0 + cb * 16) * KK + quad * 8;
    #pragma unroll
    for (int K16 = 0; K16 < 16; ++K16) {
      Bg[cb][K16] = *(const short8*)(gp + K16 * 32);
      Bh[cb][K16] = *(const short8*)(hp + K16 * 32);
    }
  }

  // stage half-tile s (t = c*TC + s/2, k-half = s&1) into ring buffer s&3.
  // Wave w stages rows [w*16, w*16+16): 8 DMA instrs, 2 rows each.
  // LDS slot (lane&31) of row rr holds global chunk (lane&31)^((rr&7)<<2)
  // (XOR involution; read side applies the same).
  auto stage = [&](int s) {
    unsigned short* dst = smem + (s & 3) * 16384 + wave * 4096;
    const int t = c * TC + (s >> 1);
    const unsigned short* srcb = xb + (size_t)t * (BB * KK) + (s & 1) * 256;
    #pragma unroll
    for (int j = 0; j < 8; ++j) {
      int rr  = wave * 16 + 2 * j + (lane >> 5);   // global row 0..63
      int gch = (lane & 31) ^ ((rr & 7) << 2);     // swizzled global chunk
      async_ld16(srcb + (size_t)rr * KK + gch * 8, dst + j * 512);
    }
  };

  // prologue: 3 half-tiles in flight (24 outstanding DMA per wave)
  stage(0); stage(1); stage(2);

  // chunk-scan state per (b,o) slot: y_out = SB + SA*y_in
  float SA[32], SB[32];
  #pragma unroll
  for (int s2 = 0; s2 < 32; ++s2) { SA[s2] = 1.0f; SB[s2] = 0.0f; }

  f32x4 accG[2][4], accH[2][4];
  #pragma unroll
  for (int cb = 0; cb < 2; ++cb)
    #pragma unroll
    for (int m = 0; m < 4; ++m) {
      f32x4 z = {0.0f, 0.0f, 0.0f, 0.0f};
      accG[cb][m] = z; accH[cb][m] = z;
    }

  for (int t = 0; t < TC; ++t) {
    #pragma unroll
    for (int h = 0; h < 2; ++h) {
      // counted wait: stage s=2t+h landed (own 8 loads); stages s+1,s+2
      // (16 newest) stay in flight across the barrier. FIFO retire order
      // makes this safe regardless of any earlier outstanding loads.
      if (t < TC - 1) {
        asm volatile("s_waitcnt vmcnt(16)" ::: "memory");
      } else if (h == 0) {
        asm volatile("s_waitcnt vmcnt(8)" ::: "memory");
      } else {
        asm volatile("s_waitcnt vmcnt(0)" ::: "memory");
      }
      __builtin_amdgcn_sched_barrier(0);
      __builtin_amdgcn_s_barrier();
      __builtin_amdgcn_sched_barrier(0);

      const int s = 2 * t + h;
      if (s + 3 < 2 * TC) stage(s + 3);          // refill ring 3 phases ahead

      const unsigned short* A0 = smem + (s & 3) * 16384;
      #pragma unroll
      for (int k2 = 0; k2 < 8; ++k2) {
        #pragma unroll
        for (int mt = 0; mt < 4; ++mt) {
          const int arow = mt * 16 + lcol;
          const int sl   = (k2 * 4 + quad) ^ ((lcol & 7) << 2);
          short8 a = *(const short8*)(A0 + arow * 256 + sl * 8);
          #pragma unroll
          for (int cb = 0; cb < 2; ++cb) {
            accG[cb][mt] = __builtin_amdgcn_mfma_f32_16x16x32_bf16(
                a, Bg[cb][h * 8 + k2], accG[cb][mt], 0, 0, 0);
            accH[cb][mt] = __builtin_amdgcn_mfma_f32_16x16x32_bf16(
                a, Bh[cb][h * 8 + k2], accH[cb][mt], 0, 0, 0);
          }
        }
      }
    }

    // epilogue: one t-step of the recurrence, folded into (SA,SB)
    const int tt = c * TC + t;
    const float tn = (float)tt * (1.0f / TT);
    #pragma unroll
    for (int cb = 0; cb < 2; ++cb) {
      const float rt = 2.0f * fast_sigmoid(tn * rv[cb] + rbv[cb]);
      #pragma unroll
      for (int mt = 0; mt < 4; ++mt)
        #pragma unroll
        for (int reg = 0; reg < 4; ++reg) {
          float G = fast_sigmoid(accG[cb][mt][reg] + gbv[cb]) * rt;
          float H = fast_tanh  (accH[cb][mt][reg] + hbv[cb]) * rt;
          int s2 = cb * 16 + mt * 4 + reg;
          SB[s2] = fmaf(G, SB[s2], H);
          SA[s2] *= G;
          accG[cb][mt][reg] = 0.0f;
          accH[cb][mt][reg] = 0.0f;
        }
    }
  }

  // write chunk composition: layout [c][b][o]
  #pragma unroll
  for (int cb = 0; cb < 2; ++cb)
    #pragma unroll
    for (int mt = 0; mt < 4; ++mt)
      #pragma unroll
      for (int reg = 0; reg < 4; ++reg) {
        int s2 = cb * 16 + mt * 4 + reg;
        int b = mt * 16 + quad * 4 + reg;
        size_t idx = ((size_t)c * BB + b) * OO + (o0 + cb * 16);
        chunkA[idx] = SA[s2];
        chunkB[idx] = SB[s2];
      }
}

// ---------------- kernel 4: fold chunks ----------------
__global__ void combine_k(const float* __restrict__ cA,
                          const float* __restrict__ cB,
                          float* __restrict__ out) {
  int i = blockIdx.x * blockDim.x + threadIdx.x;  // b*OO + o
  float y = 0.0f;
  #pragma unroll 8
  for (int c = 0; c < NCH; c++) {
    float A  = cA[(size_t)c * (BB * OO) + i];
    float Bv = cB[(size_t)c * (BB * OO) + i];
    y = fmaf(A, y, Bv);
  }
  out[i] = y;
}

extern "C" void kernel_launch(void* const* d_in, const int* in_sizes, int n_in,
                              void* d_out, int out_size, void* d_ws, size_t ws_size,
                              hipStream_t stream) {
  (void)in_sizes; (void)n_in; (void)out_size; (void)ws_size;
  const float* x  = (const float*)d_in[0];
  const float* g  = (const float*)d_in[1];
  const float* gb = (const float*)d_in[2];
  const float* h  = (const float*)d_in[3];
  const float* hb = (const float*)d_in[4];
  const float* r  = (const float*)d_in[5];
  const float* rb = (const float*)d_in[6];
  float* out = (float*)d_out;

  char* w = (char*)d_ws;
  unsigned short* xb = (unsigned short*)w;                       // 134217728 B
  unsigned short* Gt = (unsigned short*)(w + 134217728);         // 524288 B
  unsigned short* Ht = (unsigned short*)(w + 134742016);         // 524288 B
  float* chunkA = (float*)(w + 135266304);                       // 8388608 B
  float* chunkB = (float*)(w + 143654912);                       // 8388608 B
  // total: 152043520 B

  static bool attr_set = false;
  if (!attr_set) {
    hipFuncSetAttribute(reinterpret_cast<const void*>(rnn_fused5_k),
                        hipFuncAttributeMaxDynamicSharedMemorySize, 131072);
    attr_set = true;
  }

  const int n4 = (TT * BB * KK) / 4;  // 16777216 float4s
  convert_x_k<<<8192, 256, 0, stream>>>((const float4*)x, (ushort4*)xb, n4);
  prep_weights_k<<<dim3(16, 16, 2), dim3(32, 8), 0, stream>>>(g, h, Gt, Ht);
  rnn_fused5_k<<<NCH * 4, 256, 131072, stream>>>(xb, Gt, Ht, gb, hb, r, rb,
                                                 chunkA, chunkB);
  combine_k<<<(BB * OO) / 256, 256, 0, stream>>>(chunkA, chunkB, out);
}

// Round 4
// 540.611 us; speedup vs baseline: 1.0316x; 1.0316x over previous
//
#include <hip/hip_runtime.h>
#include <cstdint>
#include <cstddef>

// Problem constants
#define TT   2048
#define BB   64
#define KK   512
#define OO   512
#define NCH  64      // time chunks
#define TC   32      // t-steps per chunk

typedef __attribute__((ext_vector_type(8))) short short8;
typedef __attribute__((ext_vector_type(4))) float f32x4;

__device__ __forceinline__ unsigned short f2bf(float f) {
  unsigned int u = __float_as_uint(f);
  unsigned int rounding = 0x7FFFu + ((u >> 16) & 1u);
  return (unsigned short)((u + rounding) >> 16);
}

// fast gates: v_rcp_f32-based, no division sequence.
__device__ __forceinline__ float fast_sigmoid(float z) {
  return __builtin_amdgcn_rcpf(1.0f + __expf(-z));
}
// tanh(z) = 2*sigmoid(2z) - 1; limits exact at +-inf, no clamp needed.
__device__ __forceinline__ float fast_tanh(float z) {
  return fmaf(2.0f, __builtin_amdgcn_rcpf(1.0f + __expf(-2.0f * z)), -1.0f);
}

__device__ __forceinline__ void async_ld16(const void* g, void* l) {
  __builtin_amdgcn_global_load_lds(
      (const __attribute__((address_space(1))) void*)g,
      (__attribute__((address_space(3))) void*)l, 16, 0, 0);
}

// MFMA with EXPLICIT register-class placement (the round-4 fix).
// gfx950 arch VGPRs cap at 256; the 256-reg weight set must straddle the
// unified file: half the weights + all accumulators live in AGPRs ("a"),
// the other half in VGPRs ("v"). MFMA reads A/B/C from either class
// (cdna4_isa 10), so steady-state has ZERO cross-file moves in the K-loop.
__device__ __forceinline__ void mfma_bA(f32x4& d, short8 a, short8 b) {
  asm("v_mfma_f32_16x16x32_bf16 %0, %1, %2, %0" : "+a"(d) : "v"(a), "a"(b));
}
__device__ __forceinline__ void mfma_bV(f32x4& d, short8 a, short8 b) {
  asm("v_mfma_f32_16x16x32_bf16 %0, %1, %2, %0" : "+a"(d) : "v"(a), "v"(b));
}

// ---------------- kernel 1: x fp32 -> bf16 ----------------
__global__ void convert_x_k(const float4* __restrict__ x4,
                            ushort4* __restrict__ xb4, int n4) {
  int i = blockIdx.x * blockDim.x + threadIdx.x;
  int stride = gridDim.x * blockDim.x;
  for (; i < n4; i += stride) {
    float4 v = x4[i];
    ushort4 o;
    o.x = f2bf(v.x); o.y = f2bf(v.y); o.z = f2bf(v.z); o.w = f2bf(v.w);
    xb4[i] = o;
  }
}

// ---------------- kernel 2: transpose+convert weights ----------------
__global__ void prep_weights_k(const float* __restrict__ g,
                               const float* __restrict__ h,
                               unsigned short* __restrict__ Gt,
                               unsigned short* __restrict__ Ht) {
  __shared__ float tile[32][33];
  const float* src = (blockIdx.z == 0) ? g : h;
  unsigned short* dst = (blockIdx.z == 0) ? Gt : Ht;
  int ox = blockIdx.x * 32;   // o base
  int ky = blockIdx.y * 32;   // k base
  int tx = threadIdx.x, ty = threadIdx.y;
  #pragma unroll
  for (int r = ty; r < 32; r += 8)
    tile[r][tx] = src[(ky + r) * OO + ox + tx];
  __syncthreads();
  #pragma unroll
  for (int r = ty; r < 32; r += 8)
    dst[(size_t)(ox + r) * KK + ky + tx] = f2bf(tile[tx][r]);
}

// ---------------- kernel 3: register-B fused GEMM + gates + scan ----------
// 256 blocks (1/CU), 256 threads = 4 waves (1/SIMD). Each wave owns 32
// o-cols (2 col-blocks of 16) of BOTH G and H. Register budget per wave
// (512 unified regs at 1 wave/SIMD, arch caps 256 VGPR + 256 AGPR):
//   AGPR: Bg[0]/Bh[0] weights 128 + acc 64            = 192
//   VGPR: Bg[1]/Bh[1] weights 128 + SA/SB 32 + temps  ~ 200
// Round-3's single-class version spilled (VGPR 240 + 7.7MB scratch WRITE);
// this placement has slack in both files -> no spill, clean K-loop.
//
// LDS: 4-buffer ring of 32KB half-tiles (64 rows x 256 k bf16), 3 stages
// prefetched, counted s_waitcnt vmcnt(16) (8 DMA/wave/stage, FIFO), stage
// s+3 issued after the barrier. Swizzle: LDS slot (lane&31) of row rr holds
// global chunk (lane&31)^((rr&7)<<2); read side applies same XOR.
__global__ __launch_bounds__(256, 1) void rnn_fused6_k(
    const unsigned short* __restrict__ xb,   // [T*B][K] bf16
    const unsigned short* __restrict__ Gt,   // [OO][KK] bf16
    const unsigned short* __restrict__ Ht,   // [OO][KK] bf16
    const float* __restrict__ gb, const float* __restrict__ hb,
    const float* __restrict__ r,  const float* __restrict__ rb,
    float* __restrict__ chunkA, float* __restrict__ chunkB) {
  extern __shared__ __align__(16) unsigned short smem[];  // 4 x [64][256]

  const int tid  = threadIdx.x;
  const int wave = tid >> 6;   // 0..3
  const int lane = tid & 63;
  const int quad = lane >> 4;
  const int lcol = lane & 15;

  // bi = ot*64 + c: the 4 o-tiles of chunk c share bi%8 -> same XCD (L2 reuse)
  const int bi = blockIdx.x;
  const int ot = bi >> 6;      // 0..3
  const int c  = bi & 63;      // 0..63
  const int o0 = ot * 128 + wave * 32 + lcol;  // col-block cb adds 16

  float gbv[2], hbv[2], rv[2], rbv[2];
  #pragma unroll
  for (int cb = 0; cb < 2; ++cb) {
    int o = o0 + cb * 16;
    gbv[cb] = gb[o]; hbv[cb] = hb[o];
    rv[cb]  = r[o];  rbv[cb] = rb[o];
  }

  // ---- weights into registers: 2 col-blocks x K512 x {G,H} ----
  // cb=0 -> AGPR home (all uses are "a" operands); cb=1 -> VGPR home.
  short8 Bg0[16], Bh0[16], Bg1[16], Bh1[16];
  {
    const unsigned short* gp0 = Gt + (size_t)o0 * KK + quad * 8;
    const unsigned short* hp0 = Ht + (size_t)o0 * KK + quad * 8;
    const unsigned short* gp1 = gp0 + (size_t)16 * KK;
    const unsigned short* hp1 = hp0 + (size_t)16 * KK;
    #pragma unroll
    for (int K16 = 0; K16 < 16; ++K16) {
      Bg0[K16] = *(const short8*)(gp0 + K16 * 32);
      Bh0[K16] = *(const short8*)(hp0 + K16 * 32);
      Bg1[K16] = *(const short8*)(gp1 + K16 * 32);
      Bh1[K16] = *(const short8*)(hp1 + K16 * 32);
    }
  }

  // stage half-tile s (t = c*TC + s/2, k-half = s&1) into ring buffer s&3.
  // Wave w stages rows [w*16, w*16+16): 8 DMA instrs, 2 rows each.
  auto stage = [&](int s) {
    unsigned short* dst = smem + (s & 3) * 16384 + wave * 4096;
    const int t = c * TC + (s >> 1);
    const unsigned short* srcb = xb + (size_t)t * (BB * KK) + (s & 1) * 256;
    #pragma unroll
    for (int j = 0; j < 8; ++j) {
      int rr  = wave * 16 + 2 * j + (lane >> 5);   // global row 0..63
      int gch = (lane & 31) ^ ((rr & 7) << 2);     // swizzled global chunk
      async_ld16(srcb + (size_t)rr * KK + gch * 8, dst + j * 512);
    }
  };

  // prologue: 3 half-tiles in flight. (Any still-outstanding weight loads
  // are older in the per-wave FIFO, so the loop's vmcnt(16) naturally
  // retires them first -- counting stays correct.)
  stage(0); stage(1); stage(2);

  // chunk-scan state per (b,o) slot: y_out = SB + SA*y_in
  float SA[32], SB[32];
  #pragma unroll
  for (int s2 = 0; s2 < 32; ++s2) { SA[s2] = 1.0f; SB[s2] = 0.0f; }

  // accumulators: AGPR-homed ("+a" on every MFMA; accvgpr_read only in
  // the per-t epilogue).
  f32x4 accG[2][4], accH[2][4];
  #pragma unroll
  for (int cb = 0; cb < 2; ++cb)
    #pragma unroll
    for (int m = 0; m < 4; ++m) {
      f32x4 z = {0.0f, 0.0f, 0.0f, 0.0f};
      accG[cb][m] = z; accH[cb][m] = z;
    }

  for (int t = 0; t < TC; ++t) {
    #pragma unroll
    for (int h = 0; h < 2; ++h) {
      // counted wait: stage s=2t+h landed (own 8 loads); stages s+1,s+2
      // (16 newest) stay in flight across the barrier.
      if (t < TC - 1) {
        asm volatile("s_waitcnt vmcnt(16)" ::: "memory");
      } else if (h == 0) {
        asm volatile("s_waitcnt vmcnt(8)" ::: "memory");
      } else {
        asm volatile("s_waitcnt vmcnt(0)" ::: "memory");
      }
      __builtin_amdgcn_sched_barrier(0);
      __builtin_amdgcn_s_barrier();
      __builtin_amdgcn_sched_barrier(0);

      const int s = 2 * t + h;
      if (s + 3 < 2 * TC) stage(s + 3);          // refill ring 3 phases ahead

      const unsigned short* A0 = smem + (s & 3) * 16384;
      #pragma unroll
      for (int k2 = 0; k2 < 8; ++k2) {
        const int K16 = h * 8 + k2;
        #pragma unroll
        for (int mt = 0; mt < 4; ++mt) {
          const int arow = mt * 16 + lcol;
          const int sl   = (k2 * 4 + quad) ^ ((lcol & 7) << 2);
          short8 a = *(const short8*)(A0 + arow * 256 + sl * 8);
          mfma_bA(accG[0][mt], a, Bg0[K16]);
          mfma_bA(accH[0][mt], a, Bh0[K16]);
          mfma_bV(accG[1][mt], a, Bg1[K16]);
          mfma_bV(accH[1][mt], a, Bh1[K16]);
        }
      }
    }

    // epilogue: one t-step of the recurrence, folded into (SA,SB)
    const int tt = c * TC + t;
    const float tn = (float)tt * (1.0f / TT);
    #pragma unroll
    for (int cb = 0; cb < 2; ++cb) {
      const float rt = 2.0f * fast_sigmoid(tn * rv[cb] + rbv[cb]);
      #pragma unroll
      for (int mt = 0; mt < 4; ++mt)
        #pragma unroll
        for (int reg = 0; reg < 4; ++reg) {
          float G = fast_sigmoid(accG[cb][mt][reg] + gbv[cb]) * rt;
          float H = fast_tanh  (accH[cb][mt][reg] + hbv[cb]) * rt;
          int s2 = cb * 16 + mt * 4 + reg;
          SB[s2] = fmaf(G, SB[s2], H);
          SA[s2] *= G;
          accG[cb][mt][reg] = 0.0f;
          accH[cb][mt][reg] = 0.0f;
        }
    }
  }

  // write chunk composition: layout [c][b][o]
  #pragma unroll
  for (int cb = 0; cb < 2; ++cb)
    #pragma unroll
    for (int mt = 0; mt < 4; ++mt)
      #pragma unroll
      for (int reg = 0; reg < 4; ++reg) {
        int s2 = cb * 16 + mt * 4 + reg;
        int b = mt * 16 + quad * 4 + reg;
        size_t idx = ((size_t)c * BB + b) * OO + (o0 + cb * 16);
        chunkA[idx] = SA[s2];
        chunkB[idx] = SB[s2];
      }
}

// ---------------- kernel 4: fold chunks ----------------
__global__ void combine_k(const float* __restrict__ cA,
                          const float* __restrict__ cB,
                          float* __restrict__ out) {
  int i = blockIdx.x * blockDim.x + threadIdx.x;  // b*OO + o
  float y = 0.0f;
  #pragma unroll 8
  for (int c = 0; c < NCH; c++) {
    float A  = cA[(size_t)c * (BB * OO) + i];
    float Bv = cB[(size_t)c * (BB * OO) + i];
    y = fmaf(A, y, Bv);
  }
  out[i] = y;
}

extern "C" void kernel_launch(void* const* d_in, const int* in_sizes, int n_in,
                              void* d_out, int out_size, void* d_ws, size_t ws_size,
                              hipStream_t stream) {
  (void)in_sizes; (void)n_in; (void)out_size; (void)ws_size;
  const float* x  = (const float*)d_in[0];
  const float* g  = (const float*)d_in[1];
  const float* gb = (const float*)d_in[2];
  const float* h  = (const float*)d_in[3];
  const float* hb = (const float*)d_in[4];
  const float* r  = (const float*)d_in[5];
  const float* rb = (const float*)d_in[6];
  float* out = (float*)d_out;

  char* w = (char*)d_ws;
  unsigned short* xb = (unsigned short*)w;                       // 134217728 B
  unsigned short* Gt = (unsigned short*)(w + 134217728);         // 524288 B
  unsigned short* Ht = (unsigned short*)(w + 134742016);         // 524288 B
  float* chunkA = (float*)(w + 135266304);                       // 8388608 B
  float* chunkB = (float*)(w + 143654912);                       // 8388608 B
  // total: 152043520 B

  static bool attr_set = false;
  if (!attr_set) {
    hipFuncSetAttribute(reinterpret_cast<const void*>(rnn_fused6_k),
                        hipFuncAttributeMaxDynamicSharedMemorySize, 131072);
    attr_set = true;
  }

  const int n4 = (TT * BB * KK) / 4;  // 16777216 float4s
  convert_x_k<<<8192, 256, 0, stream>>>((const float4*)x, (ushort4*)xb, n4);
  prep_weights_k<<<dim3(16, 16, 2), dim3(32, 8), 0, stream>>>(g, h, Gt, Ht);
  rnn_fused6_k<<<NCH * 4, 256, 131072, stream>>>(xb, Gt, Ht, gb, hb, r, rb,
                                                 chunkA, chunkB);
  combine_k<<<(BB * OO) / 256, 256, 0, stream>>>(chunkA, chunkB, out);
}